// Round 5
// baseline (746.862 us; speedup 1.0000x reference)
//
#include <hip/hip_runtime.h>
#include <stdint.h>

#define LVLS 16
#define TSZ (1u << 19)
#define PR1 2654435761u
#define PR2 805459861u
#define PR3 3674653429u

// ------- Fused kernel v2: encode + SAME-XCD last-arriver MLP (no fences) -----
// Round-3's 30x regression was the per-block device-scope __threadfence (L2
// writeback x 16K blocks). Removed by construction: chunk c's 64 producer
// sub-blocks AND its consumer all run on XCD c/chPerXcd (xcd = bid&7 mapping —
// the same mapping the level-pinned 93MB-FETCH encode already relies on).
// Visibility needs only stores-drained-to-local-L2: __syncthreads (emits
// s_waitcnt vmcnt(0) before s_barrier) + device-scope atomicAdd. Slot order
// sweeps levels sequentially per XCD (phase = 512 slots >= 2x ~256 resident
// blocks, so the L2 keeps ~1 level slice hot). Encode: 32 pts/block, 8 thr/pt,
// 2 gathers/thread, shfl_xor(1,2,4) reduce. MLP (64th arriver): 2 passes x
// 64 pts, 1 pt/lane, wave w owns cols [16w,16w+16) (weights stay s_load),
// enc read from global (XCD-local L2 hit). VGPR capped 64, LDS 16.4KB ->
// 8 blocks/CU preserved for the gather pipe.
__global__ __launch_bounds__(256, 8) void fused2_kernel(
    const float* __restrict__ img, const float* __restrict__ pose,
    const float* __restrict__ table, const float* __restrict__ W1,
    const float* __restrict__ W2, const float* __restrict__ W3,
    float* __restrict__ encbuf, int* __restrict__ counters,
    float* __restrict__ out, int npts, int chPerXcd)
{
    __shared__ __align__(16) char ldsbuf[64 * 64 * 4];   // 16 KB
    __shared__ int lastFlag;
    float (*h1S)[64]   = (float (*)[64])ldsbuf;          // [64 cols][64 pts]
    float (*oS)[64][9] = (float (*)[64][9])ldsbuf;       // [4][64][9] (reuse)

    const int bid   = blockIdx.x;
    const int xcd   = bid & 7;
    const int slot  = bid >> 3;
    const int phase = chPerXcd * 4;              // slots per level per XCD
    const int level = slot / phase;
    const int rem   = slot - level * phase;
    const int chunk = xcd * chPerXcd + (rem >> 2);
    const int sub   = rem & 3;
    const int tid   = threadIdx.x;

    // ---------------- encode: 32 pts/block, 8 threads/pt ----------------
    {
        const int t  = tid & 7;
        const int s0b = t & 1, s1b = (t >> 1) & 1, s2b = (t >> 2) & 1;
        const int p  = chunk * 128 + sub * 32 + (tid >> 3);

        const float2 xi = ((const float2*)img)[p];
        const float2 xp = ((const float2*)pose)[p];

        constexpr float resv[LVLS] = {16.f, 22.f, 30.f, 42.f, 58.f, 80.f, 110.f, 152.f,
                                      210.f, 290.f, 400.f, 553.f, 763.f, 1053.f, 1453.f, 2005.f};
        const float rr = resv[level];

        const float a0 = xi.x * rr, a1 = xi.y * rr, a2 = xp.x * rr, a3 = xp.y * rr;
        const float p0f = floorf(a0), p1f = floorf(a1), p2f = floorf(a2), p3f = floorf(a3);
        const float f0 = a0 - p0f, f1 = a1 - p1f, f2 = a2 - p2f, f3 = a3 - p3f;
        const uint32_t q0 = (uint32_t)p0f, q1 = (uint32_t)p1f,
                       q2 = (uint32_t)p2f, q3 = (uint32_t)p3f;

        const uint32_t b0  = q0 + (uint32_t)s0b;
        const uint32_t hh1 = q1 * PR1 + (s1b ? PR1 : 0u);
        const uint32_t hh2 = q2 * PR2 + (s2b ? PR2 : 0u);
        const uint32_t h3a = q3 * PR3, h3b = h3a + PR3;
        const uint32_t loff = (uint32_t)level * TSZ;
        const uint32_t msk  = TSZ - 1u;
        const uint32_t bx   = b0 ^ hh1 ^ hh2;

        const float2* __restrict__ tab2 = (const float2*)table;
        const float2 fA = tab2[((bx ^ h3a) & msk) + loff];
        const float2 fB = tab2[((bx ^ h3b) & msk) + loff];

        const float w0 = s0b ? f0 : 1.f - f0;
        const float w1 = s1b ? f1 : 1.f - f1;
        const float w2 = s2b ? f2 : 1.f - f2;
        const float wb = w0 * w1 * w2;
        const float w3a = 1.f - f3;

        float e0 = wb * fmaf(w3a, fA.x, f3 * fB.x);
        float e1 = wb * fmaf(w3a, fA.y, f3 * fB.y);

        e0 += __shfl_xor(e0, 1);  e1 += __shfl_xor(e1, 1);
        e0 += __shfl_xor(e0, 2);  e1 += __shfl_xor(e1, 2);
        e0 += __shfl_xor(e0, 4);  e1 += __shfl_xor(e1, 4);

        if (t == 0)
            ((float2*)encbuf)[(size_t)level * npts + p] = make_float2(e0, e1);
    }

    // ---------------- completion protocol (same-XCD, no fences) -------------
    __threadfence_block();    // compiler ordering; no cache ops
    __syncthreads();          // drains vmcnt(0): stores are in this XCD's L2
    if (tid == 0)
        lastFlag = (atomicAdd(&counters[chunk], 1) == 63);
    __syncthreads();
    if (!lastFlag) return;

    // ---------------- MLP (64th arriver only): 2 passes x 64 pts ------------
    const int lane = tid & 63;
    const int w    = tid >> 6;                   // 0..3
    const float* __restrict__ W1w = W1 + 16 * w;
    const float* __restrict__ W2w = W2 + 16 * w;
    const float* __restrict__ W3w = W3 + (16 * w) * 9;
    const float2* __restrict__ e2 = (const float2*)encbuf;

    #pragma unroll
    for (int P = 0; P < 2; ++P) {
        const int pb = chunk * 128 + 64 * P;

        float acc[16];
        #pragma unroll
        for (int j = 0; j < 16; ++j) acc[j] = 0.f;
        #pragma unroll
        for (int l = 0; l < LVLS; ++l) {
            const float2 e = e2[(size_t)l * npts + pb + lane];
            #pragma unroll
            for (int j = 0; j < 16; ++j) {
                acc[j] = fmaf(e.x, W1w[(2 * l) * 64 + j], acc[j]);
                acc[j] = fmaf(e.y, W1w[(2 * l + 1) * 64 + j], acc[j]);
            }
        }
        #pragma unroll
        for (int j = 0; j < 16; ++j)
            h1S[16 * w + j][lane] = fmaxf(acc[j], 0.f);
        __syncthreads();

        float g[16];
        #pragma unroll
        for (int j = 0; j < 16; ++j) g[j] = 0.f;
        #pragma unroll
        for (int i = 0; i < 64; ++i) {
            const float hv = h1S[i][lane];
            #pragma unroll
            for (int j = 0; j < 16; ++j)
                g[j] = fmaf(hv, W2w[i * 64 + j], g[j]);
        }
        #pragma unroll
        for (int j = 0; j < 16; ++j) g[j] = fmaxf(g[j], 0.f);

        float o[9];
        #pragma unroll
        for (int k = 0; k < 9; ++k) o[k] = 0.f;
        #pragma unroll
        for (int j = 0; j < 16; ++j) {
            #pragma unroll
            for (int k = 0; k < 9; ++k)
                o[k] = fmaf(g[j], W3w[j * 9 + k], o[k]);
        }

        __syncthreads();      // h1S reads done; reuse region as oS
        #pragma unroll
        for (int k = 0; k < 9; ++k)
            oS[w][lane][k] = o[k];
        __syncthreads();

        for (int t2 = tid; t2 < 576; t2 += 256) {
            const int p = t2 / 9;
            const int k = t2 - 9 * p;
            out[(size_t)9 * (pb + p) + k] =
                (oS[0][p][k] + oS[1][p][k]) + (oS[2][p][k] + oS[3][p][k]);
        }
        __syncthreads();      // protect region before pass-2 h1S writes
    }
}

// ---------------- Split path A: encode (round-0 frozen, ~97us) ---------------
__global__ __launch_bounds__(256, 8) void encode_kernel(
    const float* __restrict__ img, const float* __restrict__ pose,
    const float* __restrict__ table, float* __restrict__ encbuf,
    int npts, int Bper)
{
    const int bid = blockIdx.x;
    const int grp = 8 * Bper;
    const int level = (bid % 8) + 8 * (bid / grp);
    const int within = (bid % grp) / 8;

    const int idx = within * 256 + threadIdx.x;
    const int p = idx >> 1;
    const int s = idx & 1;
    if (p >= npts) return;

    const float2 xi = ((const float2*)img)[p];
    const float2 xp = ((const float2*)pose)[p];

    constexpr float resv[LVLS] = {16.f, 22.f, 30.f, 42.f, 58.f, 80.f, 110.f, 152.f,
                                  210.f, 290.f, 400.f, 553.f, 763.f, 1053.f, 1453.f, 2005.f};
    const float rr = resv[level];

    const float s0 = xi.x * rr, s1 = xi.y * rr, s2 = xp.x * rr, s3 = xp.y * rr;
    const float p0f = floorf(s0), p1f = floorf(s1), p2f = floorf(s2), p3f = floorf(s3);
    const float f0 = s0 - p0f, f1 = s1 - p1f, f2 = s2 - p2f, f3 = s3 - p3f;
    const uint32_t q0 = (uint32_t)p0f, q1 = (uint32_t)p1f,
                   q2 = (uint32_t)p2f, q3 = (uint32_t)p3f;

    const uint32_t b0  = q0 + (uint32_t)s;
    const uint32_t h1a = q1 * PR1, h1b = h1a + PR1;
    const uint32_t h2a = q2 * PR2, h2b = h2a + PR2;
    const uint32_t h3a = q3 * PR3, h3b = h3a + PR3;
    const uint32_t loff = (uint32_t)level * TSZ;

    const float2* __restrict__ tab2 = (const float2*)table;

    float2 f[8];
    #pragma unroll
    for (int c = 0; c < 8; ++c) {
        const uint32_t h = b0 ^ ((c & 1) ? h1b : h1a)
                              ^ ((c & 2) ? h2b : h2a)
                              ^ ((c & 4) ? h3b : h3a);
        f[c] = tab2[(h & (TSZ - 1u)) + loff];
    }

    const float w0 = s ? f0 : 1.f - f0;
    const float w1a = 1.f - f1, w2a = 1.f - f2, w3a = 1.f - f3;

    float e0 = 0.f, e1 = 0.f;
    #pragma unroll
    for (int c = 0; c < 8; ++c) {
        const float w = w0 * ((c & 1) ? f1 : w1a)
                           * ((c & 2) ? f2 : w2a)
                           * ((c & 4) ? f3 : w3a);
        e0 = fmaf(w, f[c].x, e0);
        e1 = fmaf(w, f[c].y, e1);
    }

    e0 += __shfl_xor(e0, 1);
    e1 += __shfl_xor(e1, 1);

    if (s == 0)
        ((float2*)encbuf)[(size_t)level * npts + p] = make_float2(e0, e1);
}

// ---------------- Split path B: MLP (round-2 version) ------------------------
__global__ __launch_bounds__(256, 4) void mlp_kernel(
    const float* __restrict__ encbuf, const float* __restrict__ W1,
    const float* __restrict__ W2, const float* __restrict__ W3,
    float* __restrict__ out, int npts)
{
    __shared__ __align__(16) char ldsbuf[64 * 64 * sizeof(float2)];   // 32 KB
    float2 (*h1P)[64]   = (float2 (*)[64])ldsbuf;
    float2 (*oS)[64][9] = (float2 (*)[64][9])ldsbuf;

    const int lane = threadIdx.x & 63;
    const int w    = __builtin_amdgcn_readfirstlane(threadIdx.x >> 6);
    const int base = blockIdx.x * 128;
    const int pA   = base + lane;
    const int pB   = pA + 64;

    const float* __restrict__ W1w = W1 + 16 * w;
    float hA[16], hB[16];
    #pragma unroll
    for (int j = 0; j < 16; ++j) { hA[j] = 0.f; hB[j] = 0.f; }
    const float2* e2 = (const float2*)encbuf;
    #pragma unroll
    for (int l = 0; l < LVLS; ++l) {
        const float2 eA = e2[(size_t)l * npts + pA];
        const float2 eB = e2[(size_t)l * npts + pB];
        #pragma unroll
        for (int j = 0; j < 16; ++j) {
            const float w0 = W1w[(2 * l) * 64 + j];
            const float w1 = W1w[(2 * l + 1) * 64 + j];
            hA[j] = fmaf(eA.x, w0, hA[j]); hA[j] = fmaf(eA.y, w1, hA[j]);
            hB[j] = fmaf(eB.x, w0, hB[j]); hB[j] = fmaf(eB.y, w1, hB[j]);
        }
    }
    #pragma unroll
    for (int j = 0; j < 16; ++j)
        h1P[16 * w + j][lane] = make_float2(fmaxf(hA[j], 0.f), fmaxf(hB[j], 0.f));
    __syncthreads();

    const float* __restrict__ W2w = W2 + 16 * w;
    float gA[16], gB[16];
    #pragma unroll
    for (int j = 0; j < 16; ++j) { gA[j] = 0.f; gB[j] = 0.f; }
    #pragma unroll
    for (int i = 0; i < 64; ++i) {
        const float2 hv = h1P[i][lane];
        #pragma unroll
        for (int j = 0; j < 16; ++j) {
            const float wv = W2w[i * 64 + j];
            gA[j] = fmaf(hv.x, wv, gA[j]);
            gB[j] = fmaf(hv.y, wv, gB[j]);
        }
    }
    #pragma unroll
    for (int j = 0; j < 16; ++j) { gA[j] = fmaxf(gA[j], 0.f); gB[j] = fmaxf(gB[j], 0.f); }

    const float* __restrict__ W3w = W3 + (16 * w) * 9;
    float oA[9], oB[9];
    #pragma unroll
    for (int k = 0; k < 9; ++k) { oA[k] = 0.f; oB[k] = 0.f; }
    #pragma unroll
    for (int j = 0; j < 16; ++j) {
        #pragma unroll
        for (int k = 0; k < 9; ++k) {
            const float wv = W3w[j * 9 + k];
            oA[k] = fmaf(gA[j], wv, oA[k]);
            oB[k] = fmaf(gB[j], wv, oB[k]);
        }
    }

    __syncthreads();
    #pragma unroll
    for (int k = 0; k < 9; ++k)
        oS[w][lane][k] = make_float2(oA[k], oB[k]);
    __syncthreads();

    for (int t = threadIdx.x; t < 576; t += 256) {
        const int p = t / 9;
        const int k = t - 9 * p;
        const float2 s0 = oS[0][p][k];
        const float2 s1 = oS[1][p][k];
        const float2 s2 = oS[2][p][k];
        const float2 s3 = oS[3][p][k];
        out[(size_t)9 * (base + p) + k]      = (s0.x + s1.x) + (s2.x + s3.x);
        out[(size_t)9 * (base + p + 64) + k] = (s0.y + s1.y) + (s2.y + s3.y);
    }
}

// ---------------- Fallback: fused single kernel (round-1, known-good) --------
__global__ __launch_bounds__(256) void hashgrid_mlp_kernel(
    const float* __restrict__ img, const float* __restrict__ pose,
    const float* __restrict__ table, const float* __restrict__ W1,
    const float* __restrict__ W2, const float* __restrict__ W3,
    float* __restrict__ out)
{
    const int n = blockIdx.x * 256 + threadIdx.x;

    const float x0 = img[2 * n], x1 = img[2 * n + 1];
    const float x2 = pose[2 * n], x3 = pose[2 * n + 1];

    const float resv[LVLS] = {16.f, 22.f, 30.f, 42.f, 58.f, 80.f, 110.f, 152.f,
                              210.f, 290.f, 400.f, 553.f, 763.f, 1053.f, 1453.f, 2005.f};

    const float2* __restrict__ tab2 = (const float2*)table;

    float enc[32];

    #pragma unroll
    for (int l = 0; l < LVLS; ++l) {
        const float r = resv[l];
        const float s0 = x0 * r, s1 = x1 * r, s2 = x2 * r, s3 = x3 * r;
        const float p0 = floorf(s0), p1 = floorf(s1), p2 = floorf(s2), p3 = floorf(s3);
        const float f0 = s0 - p0, f1 = s1 - p1, f2 = s2 - p2, f3 = s3 - p3;
        const uint32_t q0 = (uint32_t)p0, q1 = (uint32_t)p1,
                       q2 = (uint32_t)p2, q3 = (uint32_t)p3;

        const uint32_t h1a = q1 * PR1, h1b = h1a + PR1;
        const uint32_t h2a = q2 * PR2, h2b = h2a + PR2;
        const uint32_t h3a = q3 * PR3, h3b = h3a + PR3;
        const float w0a = 1.f - f0, w1a = 1.f - f1, w2a = 1.f - f2, w3a = 1.f - f3;

        float2 feat[16];
        #pragma unroll
        for (int c = 0; c < 16; ++c) {
            const uint32_t h = (q0 + (c & 1))
                             ^ ((c & 2) ? h1b : h1a)
                             ^ ((c & 4) ? h2b : h2a)
                             ^ ((c & 8) ? h3b : h3a);
            const uint32_t idx = (h & (TSZ - 1u)) + (uint32_t)l * TSZ;
            feat[c] = tab2[idx];
        }

        float e0 = 0.f, e1 = 0.f;
        #pragma unroll
        for (int c = 0; c < 16; ++c) {
            const float w = ((c & 1) ? f0 : w0a) * ((c & 2) ? f1 : w1a)
                          * ((c & 4) ? f2 : w2a) * ((c & 8) ? f3 : w3a);
            e0 = fmaf(w, feat[c].x, e0);
            e1 = fmaf(w, feat[c].y, e1);
        }
        enc[2 * l]     = e0;
        enc[2 * l + 1] = e1;
    }

    float h1[64];
    #pragma unroll
    for (int j = 0; j < 64; ++j) h1[j] = 0.f;
    #pragma unroll
    for (int i = 0; i < 32; ++i) {
        const float e = enc[i];
        #pragma unroll
        for (int j = 0; j < 64; ++j) h1[j] = fmaf(e, W1[i * 64 + j], h1[j]);
    }
    #pragma unroll
    for (int j = 0; j < 64; ++j) h1[j] = fmaxf(h1[j], 0.f);

    float h2[64];
    #pragma unroll
    for (int j = 0; j < 64; ++j) h2[j] = 0.f;
    #pragma unroll
    for (int i = 0; i < 64; ++i) {
        const float e = h1[i];
        #pragma unroll
        for (int j = 0; j < 64; ++j) h2[j] = fmaf(e, W2[i * 64 + j], h2[j]);
    }
    #pragma unroll
    for (int j = 0; j < 64; ++j) h2[j] = fmaxf(h2[j], 0.f);

    float o[9];
    #pragma unroll
    for (int j = 0; j < 9; ++j) o[j] = 0.f;
    #pragma unroll
    for (int i = 0; i < 64; ++i) {
        const float e = h2[i];
        #pragma unroll
        for (int j = 0; j < 9; ++j) o[j] = fmaf(e, W3[i * 9 + j], o[j]);
    }
    #pragma unroll
    for (int j = 0; j < 9; ++j) out[9 * n + j] = o[j];
}

extern "C" void kernel_launch(void* const* d_in, const int* in_sizes, int n_in,
                              void* d_out, int out_size, void* d_ws, size_t ws_size,
                              hipStream_t stream) {
    const float* img   = (const float*)d_in[0];
    const float* pose  = (const float*)d_in[1];
    const float* table = (const float*)d_in[2];
    const float* W1    = (const float*)d_in[3];
    const float* W2    = (const float*)d_in[4];
    const float* W3    = (const float*)d_in[5];
    float* out = (float*)d_out;

    const int n = in_sizes[0] / 2;               // number of points
    const int NCH = n / 128;                     // chunks of 128 points
    const size_t need_enc = (size_t)n * 32 * sizeof(float);
    const size_t need_fused = need_enc + (size_t)NCH * sizeof(int);

    if (ws_size >= need_fused && (n % 1024) == 0) {
        // fused path: chunks evenly split over 8 XCDs
        float* encbuf = (float*)d_ws;
        int* counters = (int*)((char*)d_ws + need_enc);
        hipMemsetAsync(counters, 0, (size_t)NCH * sizeof(int), stream);
        hipLaunchKernelGGL(fused2_kernel, dim3(NCH * 64), dim3(256), 0, stream,
                           img, pose, table, W1, W2, W3,
                           encbuf, counters, out, n, NCH / 8);
    } else if (ws_size >= need_enc && (n % 128) == 0 && ((n * 2) % 256) == 0) {
        float* encbuf = (float*)d_ws;
        const int Bper = (n * 2) / 256;
        hipLaunchKernelGGL(encode_kernel, dim3(Bper * LVLS), dim3(256), 0, stream,
                           img, pose, table, encbuf, n, Bper);
        hipLaunchKernelGGL(mlp_kernel, dim3(n / 128), dim3(256), 0, stream,
                           encbuf, W1, W2, W3, out, n);
    } else {
        hipLaunchKernelGGL(hashgrid_mlp_kernel, dim3((n + 255) / 256), dim3(256), 0, stream,
                           img, pose, table, W1, W2, W3, out);
    }
}

// Round 6
// 121.058 us; speedup vs baseline: 6.1695x; 6.1695x over previous
//
#include <hip/hip_runtime.h>
#include <stdint.h>

#define LVLS 16
#define TSZ (1u << 19)
#define PR1 2654435761u
#define PR2 805459861u
#define PR3 3674653429u

// ---------------- Kernel A: encode (round-0 frozen, ~97us) -------------------
// blockIdx round-robins across 8 XCDs: level = (bid%8) + 8*(bid/(8*B)) pins all
// blocks of a level to one XCD (its L2 holds that 4MB slice; FETCH ~= compulsory
// 93MB). 2 threads/point: thread s owns dim-0 corner bit, 8 float2 gathers,
// pair shfl reduce, s==0 writes transposed enc_t[l*N+p].
// Encode is at the random-gather L2 ceiling. Two attacks failed:
//  - paired dwordx4 (r4): exec-mask serialization doubled VALU, +33% time.
//  - fusion (r3 device-fence: L2 flush x16K blocks, 30x; r5 same-XCD level
//    sweep: 4MB slice swap per level transition, FETCH 93->380MB, 6x).
// The whole-level-resident dispatch below is load-bearing. DO NOT TOUCH.
__global__ __launch_bounds__(256, 8) void encode_kernel(
    const float* __restrict__ img, const float* __restrict__ pose,
    const float* __restrict__ table, float* __restrict__ encbuf,
    int npts, int Bper)
{
    const int bid = blockIdx.x;
    const int grp = 8 * Bper;
    const int level = (bid % 8) + 8 * (bid / grp);
    const int within = (bid % grp) / 8;

    const int idx = within * 256 + threadIdx.x;
    const int p = idx >> 1;
    const int s = idx & 1;
    if (p >= npts) return;

    const float2 xi = ((const float2*)img)[p];
    const float2 xp = ((const float2*)pose)[p];

    constexpr float resv[LVLS] = {16.f, 22.f, 30.f, 42.f, 58.f, 80.f, 110.f, 152.f,
                                  210.f, 290.f, 400.f, 553.f, 763.f, 1053.f, 1453.f, 2005.f};
    const float rr = resv[level];

    const float s0 = xi.x * rr, s1 = xi.y * rr, s2 = xp.x * rr, s3 = xp.y * rr;
    const float p0f = floorf(s0), p1f = floorf(s1), p2f = floorf(s2), p3f = floorf(s3);
    const float f0 = s0 - p0f, f1 = s1 - p1f, f2 = s2 - p2f, f3 = s3 - p3f;
    const uint32_t q0 = (uint32_t)p0f, q1 = (uint32_t)p1f,
                   q2 = (uint32_t)p2f, q3 = (uint32_t)p3f;

    const uint32_t b0  = q0 + (uint32_t)s;
    const uint32_t h1a = q1 * PR1, h1b = h1a + PR1;
    const uint32_t h2a = q2 * PR2, h2b = h2a + PR2;
    const uint32_t h3a = q3 * PR3, h3b = h3a + PR3;
    const uint32_t loff = (uint32_t)level * TSZ;

    const float2* __restrict__ tab2 = (const float2*)table;

    float2 f[8];
    #pragma unroll
    for (int c = 0; c < 8; ++c) {
        const uint32_t h = b0 ^ ((c & 1) ? h1b : h1a)
                              ^ ((c & 2) ? h2b : h2a)
                              ^ ((c & 4) ? h3b : h3a);
        f[c] = tab2[(h & (TSZ - 1u)) + loff];
    }

    const float w0 = s ? f0 : 1.f - f0;
    const float w1a = 1.f - f1, w2a = 1.f - f2, w3a = 1.f - f3;

    float e0 = 0.f, e1 = 0.f;
    #pragma unroll
    for (int c = 0; c < 8; ++c) {
        const float w = w0 * ((c & 1) ? f1 : w1a)
                           * ((c & 2) ? f2 : w2a)
                           * ((c & 4) ? f3 : w3a);
        e0 = fmaf(w, f[c].x, e0);
        e1 = fmaf(w, f[c].y, e1);
    }

    e0 += __shfl_xor(e0, 1);
    e1 += __shfl_xor(e1, 1);

    if (s == 0)
        ((float2*)encbuf)[(size_t)level * npts + p] = make_float2(e0, e1);
}

// ---------------- Kernel B: MLP (round-2 structure + enc prefetch) -----------
// Block = 256 threads = 4 waves, 128 points. Lane owns point-pair; wave w owns
// cols [16w,16w+16) of h1 AND h2 (keeps scalar weight working set inside the
// SGPR budget -> all weight reads stay s_load; thread-per-point failed on
// exactly this). h1 exchanged as float2 pairs; distributed epilogue.
// Round-6 change: all 32 enc loads issued UP FRONT into registers (T14
// issue-early/consume-late) instead of interleaved per-level with their
// consuming FMAs — the per-level vmcnt chain exposed ~200cy L2 latency 16x;
// now the loads drain under the 1024-FMA h1 stream. VGPR ~110-130, still
// within the 128 cap for 4 waves/SIMD.
__global__ __launch_bounds__(256, 4) void mlp_kernel(
    const float* __restrict__ encbuf, const float* __restrict__ W1,
    const float* __restrict__ W2, const float* __restrict__ W3,
    float* __restrict__ out, int npts)
{
    __shared__ __align__(16) char ldsbuf[64 * 64 * sizeof(float2)];   // 32 KB
    float2 (*h1P)[64]   = (float2 (*)[64])ldsbuf;      // [64 rows][64 pt-pairs]
    float2 (*oS)[64][9] = (float2 (*)[64][9])ldsbuf;   // [4][64][9] (reuse)

    const int lane = threadIdx.x & 63;
    const int w    = __builtin_amdgcn_readfirstlane(threadIdx.x >> 6);   // 0..3
    const int base = blockIdx.x * 128;
    const int pA   = base + lane;
    const int pB   = pA + 64;

    // ---- prefetch: all 32 enc loads issued before any FMA ----
    const float2* __restrict__ e2 = (const float2*)encbuf;
    float2 eA[16], eB[16];
    #pragma unroll
    for (int l = 0; l < LVLS; ++l) {
        eA[l] = e2[(size_t)l * npts + pA];
        eB[l] = e2[(size_t)l * npts + pB];
    }

    // ---- h1: own 16 columns, both points ----
    const float* __restrict__ W1w = W1 + 16 * w;
    float hA[16], hB[16];
    #pragma unroll
    for (int j = 0; j < 16; ++j) { hA[j] = 0.f; hB[j] = 0.f; }
    #pragma unroll
    for (int l = 0; l < LVLS; ++l) {
        #pragma unroll
        for (int j = 0; j < 16; ++j) {
            const float w0 = W1w[(2 * l) * 64 + j];
            const float w1 = W1w[(2 * l + 1) * 64 + j];
            hA[j] = fmaf(eA[l].x, w0, hA[j]); hA[j] = fmaf(eA[l].y, w1, hA[j]);
            hB[j] = fmaf(eB[l].x, w0, hB[j]); hB[j] = fmaf(eB[l].y, w1, hB[j]);
        }
    }
    #pragma unroll
    for (int j = 0; j < 16; ++j)
        h1P[16 * w + j][lane] = make_float2(fmaxf(hA[j], 0.f), fmaxf(hB[j], 0.f));
    __syncthreads();

    // ---- h2: own 16 columns over all 64 h1 rows, both points ----
    const float* __restrict__ W2w = W2 + 16 * w;
    float gA[16], gB[16];
    #pragma unroll
    for (int j = 0; j < 16; ++j) { gA[j] = 0.f; gB[j] = 0.f; }
    #pragma unroll
    for (int i = 0; i < 64; ++i) {
        const float2 hv = h1P[i][lane];
        #pragma unroll
        for (int j = 0; j < 16; ++j) {
            const float wv = W2w[i * 64 + j];
            gA[j] = fmaf(hv.x, wv, gA[j]);
            gB[j] = fmaf(hv.y, wv, gB[j]);
        }
    }
    #pragma unroll
    for (int j = 0; j < 16; ++j) { gA[j] = fmaxf(gA[j], 0.f); gB[j] = fmaxf(gB[j], 0.f); }

    // ---- partial o[9] over own 16 h2 rows, both points ----
    const float* __restrict__ W3w = W3 + (16 * w) * 9;
    float oA[9], oB[9];
    #pragma unroll
    for (int k = 0; k < 9; ++k) { oA[k] = 0.f; oB[k] = 0.f; }
    #pragma unroll
    for (int j = 0; j < 16; ++j) {
        #pragma unroll
        for (int k = 0; k < 9; ++k) {
            const float wv = W3w[j * 9 + k];
            oA[k] = fmaf(gA[j], wv, oA[k]);
            oB[k] = fmaf(gB[j], wv, oB[k]);
        }
    }

    __syncthreads();   // h1P no longer needed; safe to reuse region as oS

    #pragma unroll
    for (int k = 0; k < 9; ++k)
        oS[w][lane][k] = make_float2(oA[k], oB[k]);
    __syncthreads();

    // ---- distributed reduce + store: 576 float2 outputs over 256 threads ----
    for (int t = threadIdx.x; t < 576; t += 256) {
        const int p = t / 9;
        const int k = t - 9 * p;
        const float2 s0 = oS[0][p][k];
        const float2 s1 = oS[1][p][k];
        const float2 s2 = oS[2][p][k];
        const float2 s3 = oS[3][p][k];
        out[(size_t)9 * (base + p) + k]      = (s0.x + s1.x) + (s2.x + s3.x);
        out[(size_t)9 * (base + p + 64) + k] = (s0.y + s1.y) + (s2.y + s3.y);
    }
}

// ---------------- Fallback: fused single kernel (round-1, known-good) --------
__global__ __launch_bounds__(256) void hashgrid_mlp_kernel(
    const float* __restrict__ img, const float* __restrict__ pose,
    const float* __restrict__ table, const float* __restrict__ W1,
    const float* __restrict__ W2, const float* __restrict__ W3,
    float* __restrict__ out)
{
    const int n = blockIdx.x * 256 + threadIdx.x;

    const float x0 = img[2 * n], x1 = img[2 * n + 1];
    const float x2 = pose[2 * n], x3 = pose[2 * n + 1];

    const float resv[LVLS] = {16.f, 22.f, 30.f, 42.f, 58.f, 80.f, 110.f, 152.f,
                              210.f, 290.f, 400.f, 553.f, 763.f, 1053.f, 1453.f, 2005.f};

    const float2* __restrict__ tab2 = (const float2*)table;

    float enc[32];

    #pragma unroll
    for (int l = 0; l < LVLS; ++l) {
        const float r = resv[l];
        const float s0 = x0 * r, s1 = x1 * r, s2 = x2 * r, s3 = x3 * r;
        const float p0 = floorf(s0), p1 = floorf(s1), p2 = floorf(s2), p3 = floorf(s3);
        const float f0 = s0 - p0, f1 = s1 - p1, f2 = s2 - p2, f3 = s3 - p3;
        const uint32_t q0 = (uint32_t)p0, q1 = (uint32_t)p1,
                       q2 = (uint32_t)p2, q3 = (uint32_t)p3;

        const uint32_t h1a = q1 * PR1, h1b = h1a + PR1;
        const uint32_t h2a = q2 * PR2, h2b = h2a + PR2;
        const uint32_t h3a = q3 * PR3, h3b = h3a + PR3;
        const float w0a = 1.f - f0, w1a = 1.f - f1, w2a = 1.f - f2, w3a = 1.f - f3;

        float2 feat[16];
        #pragma unroll
        for (int c = 0; c < 16; ++c) {
            const uint32_t h = (q0 + (c & 1))
                             ^ ((c & 2) ? h1b : h1a)
                             ^ ((c & 4) ? h2b : h2a)
                             ^ ((c & 8) ? h3b : h3a);
            const uint32_t idx = (h & (TSZ - 1u)) + (uint32_t)l * TSZ;
            feat[c] = tab2[idx];
        }

        float e0 = 0.f, e1 = 0.f;
        #pragma unroll
        for (int c = 0; c < 16; ++c) {
            const float w = ((c & 1) ? f0 : w0a) * ((c & 2) ? f1 : w1a)
                          * ((c & 4) ? f2 : w2a) * ((c & 8) ? f3 : w3a);
            e0 = fmaf(w, feat[c].x, e0);
            e1 = fmaf(w, feat[c].y, e1);
        }
        enc[2 * l]     = e0;
        enc[2 * l + 1] = e1;
    }

    float h1[64];
    #pragma unroll
    for (int j = 0; j < 64; ++j) h1[j] = 0.f;
    #pragma unroll
    for (int i = 0; i < 32; ++i) {
        const float e = enc[i];
        #pragma unroll
        for (int j = 0; j < 64; ++j) h1[j] = fmaf(e, W1[i * 64 + j], h1[j]);
    }
    #pragma unroll
    for (int j = 0; j < 64; ++j) h1[j] = fmaxf(h1[j], 0.f);

    float h2[64];
    #pragma unroll
    for (int j = 0; j < 64; ++j) h2[j] = 0.f;
    #pragma unroll
    for (int i = 0; i < 64; ++i) {
        const float e = h1[i];
        #pragma unroll
        for (int j = 0; j < 64; ++j) h2[j] = fmaf(e, W2[i * 64 + j], h2[j]);
    }
    #pragma unroll
    for (int j = 0; j < 64; ++j) h2[j] = fmaxf(h2[j], 0.f);

    float o[9];
    #pragma unroll
    for (int j = 0; j < 9; ++j) o[j] = 0.f;
    #pragma unroll
    for (int i = 0; i < 64; ++i) {
        const float e = h2[i];
        #pragma unroll
        for (int j = 0; j < 9; ++j) o[j] = fmaf(e, W3[i * 9 + j], o[j]);
    }
    #pragma unroll
    for (int j = 0; j < 9; ++j) out[9 * n + j] = o[j];
}

extern "C" void kernel_launch(void* const* d_in, const int* in_sizes, int n_in,
                              void* d_out, int out_size, void* d_ws, size_t ws_size,
                              hipStream_t stream) {
    const float* img   = (const float*)d_in[0];
    const float* pose  = (const float*)d_in[1];
    const float* table = (const float*)d_in[2];
    const float* W1    = (const float*)d_in[3];
    const float* W2    = (const float*)d_in[4];
    const float* W3    = (const float*)d_in[5];
    float* out = (float*)d_out;

    const int n = in_sizes[0] / 2;              // number of points
    const size_t need = (size_t)n * 32 * sizeof(float);

    if (ws_size >= need && (n % 128) == 0 && ((n * 2) % 256) == 0) {
        float* encbuf = (float*)d_ws;
        const int Bper = (n * 2) / 256;         // blocks per level
        hipLaunchKernelGGL(encode_kernel, dim3(Bper * LVLS), dim3(256), 0, stream,
                           img, pose, table, encbuf, n, Bper);
        hipLaunchKernelGGL(mlp_kernel, dim3(n / 128), dim3(256), 0, stream,
                           encbuf, W1, W2, W3, out, n);
    } else {
        hipLaunchKernelGGL(hashgrid_mlp_kernel, dim3((n + 255) / 256), dim3(256), 0, stream,
                           img, pose, table, W1, W2, W3, out);
    }
}